// Round 1
// baseline (544.453 us; speedup 1.0000x reference)
//
#include <hip/hip_runtime.h>
#include <cstddef>

#define B_  8
#define N_  8192
#define C_  256
#define H_  128
#define W_  128
#define HH  8
#define PP  4
#define DD  32
#define HW  (H_ * W_)

// ---------------------------------------------------------------------------
// kT: transpose value (B, C=256, H, W) -> val (B*8, H*W, 32)
// val[(b*8+h)*HW + pix][d] = value[(b*8+h)*32 + d][pix]
// ---------------------------------------------------------------------------
__global__ __launch_bounds__(256) void kT(const float* __restrict__ value,
                                          float* __restrict__ val) {
    __shared__ float tile[32][65];
    const int bh   = blockIdx.y;        // b*8 + h
    const int pix0 = blockIdx.x * 64;
    const int t    = threadIdx.x;

    const float* src = value + (size_t)bh * 32 * HW + pix0;
#pragma unroll
    for (int i = 0; i < 8; ++i) {
        int d = i * 4 + (t >> 6);
        int p = t & 63;
        tile[d][p] = src[(size_t)d * HW + p];
    }
    __syncthreads();
    float* dst = val + ((size_t)bh * HW + pix0) * 32;
#pragma unroll
    for (int j = 0; j < 8; ++j) {
        int p = j * 8 + (t >> 5);
        int d = t & 31;
        dst[(size_t)p * 32 + d] = tile[d][p];
    }
}

// ---------------------------------------------------------------------------
// kA1: offset/attn GEMM (65536x256)@(256x96) + bias + softmax + loc epilogue
// 256 threads, BM=128 rows. thread: rg = t>>3 (4 rows), h = t&7 (12 cols).
// Writes locattn[(row*8+h)*4 + p] = {x_pix, y_pix, attn, 0}
// ---------------------------------------------------------------------------
#define A1_BM 128
#define A1_BK 32

__global__ __launch_bounds__(256) void kA1(const float* __restrict__ query,
                                           const float* __restrict__ refp,
                                           const float* __restrict__ W_off,
                                           const float* __restrict__ b_off,
                                           const float* __restrict__ W_attn,
                                           const float* __restrict__ b_attn,
                                           float4* __restrict__ locattn) {
    __shared__ float At[A1_BK][A1_BM + 4];
    __shared__ float Bo[A1_BK][64];
    __shared__ float Ba[A1_BK][32];

    const int t    = threadIdx.x;
    const int row0 = blockIdx.x * A1_BM;
    const int rg   = t >> 3;   // 0..31 -> rows rg*4 .. rg*4+3
    const int h    = t & 7;

    float accO[4][8];
    float accA[4][4];
#pragma unroll
    for (int r = 0; r < 4; ++r) {
#pragma unroll
        for (int j = 0; j < 8; ++j) accO[r][j] = 0.f;
#pragma unroll
        for (int j = 0; j < 4; ++j) accA[r][j] = 0.f;
    }

    for (int k0 = 0; k0 < C_; k0 += A1_BK) {
        // stage A transposed: 128 rows x 32 k
        {
            int kq = (t & 7) * 4;
            int ra = t >> 3;   // 0..31
#pragma unroll
            for (int rr = 0; rr < 4; ++rr) {
                int r = ra + rr * 32;
                float4 q = *(const float4*)&query[(size_t)(row0 + r) * C_ + k0 + kq];
                At[kq + 0][r] = q.x;
                At[kq + 1][r] = q.y;
                At[kq + 2][r] = q.z;
                At[kq + 3][r] = q.w;
            }
        }
        // stage Bo: 32 x 64
        {
            int c4 = (t & 15) * 4;
            int kb = t >> 4;   // 0..15
#pragma unroll
            for (int i = 0; i < 2; ++i) {
                int k = kb + i * 16;
                *(float4*)&Bo[k][c4] = *(const float4*)&W_off[(size_t)(k0 + k) * 64 + c4];
            }
        }
        // stage Ba: 32 x 32
        {
            int c4 = (t & 7) * 4;
            int kb = t >> 3;   // 0..31
            *(float4*)&Ba[kb][c4] = *(const float4*)&W_attn[(size_t)(k0 + kb) * 32 + c4];
        }
        __syncthreads();

#pragma unroll
        for (int k = 0; k < A1_BK; ++k) {
            float4 a   = *(const float4*)&At[k][rg * 4];
            float4 bo0 = *(const float4*)&Bo[k][h * 8];
            float4 bo1 = *(const float4*)&Bo[k][h * 8 + 4];
            float4 ba  = *(const float4*)&Ba[k][h * 4];
            float av[4] = {a.x, a.y, a.z, a.w};
            float bO[8] = {bo0.x, bo0.y, bo0.z, bo0.w, bo1.x, bo1.y, bo1.z, bo1.w};
            float bA[4] = {ba.x, ba.y, ba.z, ba.w};
#pragma unroll
            for (int r = 0; r < 4; ++r) {
#pragma unroll
                for (int j = 0; j < 8; ++j) accO[r][j] += av[r] * bO[j];
#pragma unroll
                for (int j = 0; j < 4; ++j) accA[r][j] += av[r] * bA[j];
            }
        }
        __syncthreads();
    }

    // epilogue
    float boff[8];
#pragma unroll
    for (int j = 0; j < 8; ++j) boff[j] = b_off[h * 8 + j];
    float batn[4];
#pragma unroll
    for (int j = 0; j < 4; ++j) batn[j] = b_attn[h * 4 + j];

#pragma unroll
    for (int r = 0; r < 4; ++r) {
        int row  = row0 + rg * 4 + r;
        float rx = refp[(size_t)row * 2 + 0];
        float ry = refp[(size_t)row * 2 + 1];
        float lg[4];
#pragma unroll
        for (int p = 0; p < 4; ++p) lg[p] = accA[r][p] + batn[p];
        float m = fmaxf(fmaxf(lg[0], lg[1]), fmaxf(lg[2], lg[3]));
        float e[4];
        float s = 0.f;
#pragma unroll
        for (int p = 0; p < 4; ++p) { e[p] = __expf(lg[p] - m); s += e[p]; }
        float inv = 1.f / s;
#pragma unroll
        for (int p = 0; p < 4; ++p) {
            float ox = accO[r][p * 2 + 0] + boff[p * 2 + 0];
            float oy = accO[r][p * 2 + 1] + boff[p * 2 + 1];
            float x  = (rx * 2.f + ox) * (W_ * 0.5f) - 0.5f;
            float y  = (ry * 2.f + oy) * (H_ * 0.5f) - 0.5f;
            locattn[((size_t)row * HH + h) * PP + p] = make_float4(x, y, e[p] * inv, 0.f);
        }
    }
}

// ---------------------------------------------------------------------------
// kA2: bilinear sampling + attention weighting -> mid (B*N, 256)
// grid (N/8, B*8); block 256 = 8 rows x 32 d. Same (b,h) slab per blockIdx.y
// so co-resident blocks (linearized y-major) share a 2 MB L2-resident slab.
// ---------------------------------------------------------------------------
__global__ __launch_bounds__(256) void kA2(const float4* __restrict__ locattn,
                                           const float* __restrict__ val,
                                           float* __restrict__ mid) {
    const int t  = threadIdx.x;
    const int d  = t & 31;
    const int lr = t >> 5;            // 0..7
    const int bh = blockIdx.y;        // b*8 + h
    const int b  = bh >> 3;
    const int h  = bh & 7;
    const int n  = blockIdx.x * 8 + lr;
    const size_t row = (size_t)b * N_ + n;

    const float4* la    = &locattn[(row * HH + h) * PP];
    const float*  vbase = val + (size_t)bh * HW * DD + d;

    float acc = 0.f;
#pragma unroll
    for (int p = 0; p < PP; ++p) {
        float4 L = la[p];
        float x = L.x, y = L.y, a = L.z;
        float xf = floorf(x), yf = floorf(y);
        int x0 = (int)xf, y0 = (int)yf;
        int x1 = x0 + 1, y1 = y0 + 1;
        float wx1 = x - xf, wy1 = y - yf;
        float wx0 = 1.f - wx1, wy0 = 1.f - wy1;
        int cx0 = min(max(x0, 0), W_ - 1);
        int cx1 = min(max(x1, 0), W_ - 1);
        int cy0 = min(max(y0, 0), H_ - 1);
        int cy1 = min(max(y1, 0), H_ - 1);
        float m00 = (x0 >= 0 && x0 < W_ && y0 >= 0 && y0 < H_) ? 1.f : 0.f;
        float m10 = (x1 >= 0 && x1 < W_ && y0 >= 0 && y0 < H_) ? 1.f : 0.f;
        float m01 = (x0 >= 0 && x0 < W_ && y1 >= 0 && y1 < H_) ? 1.f : 0.f;
        float m11 = (x1 >= 0 && x1 < W_ && y1 >= 0 && y1 < H_) ? 1.f : 0.f;
        float v00 = vbase[((size_t)(cy0 * W_ + cx0)) * DD];
        float v10 = vbase[((size_t)(cy0 * W_ + cx1)) * DD];
        float v01 = vbase[((size_t)(cy1 * W_ + cx0)) * DD];
        float v11 = vbase[((size_t)(cy1 * W_ + cx1)) * DD];
        acc += a * (v00 * (wx0 * wy0 * m00) + v10 * (wx1 * wy0 * m10) +
                    v01 * (wx0 * wy1 * m01) + v11 * (wx1 * wy1 * m11));
    }
    mid[row * C_ + h * DD + d] = acc;
}

// ---------------------------------------------------------------------------
// kC: out = mid (65536x256) @ W_out (256x256) + b_out
// 128x128 tile, 256 threads (16x16), 8x8 per thread.
// ---------------------------------------------------------------------------
#define CC_BM 128
#define CC_BN 128
#define CC_BK 16

__global__ __launch_bounds__(256) void kC(const float* __restrict__ A,
                                          const float* __restrict__ Bm,
                                          const float* __restrict__ bias,
                                          float* __restrict__ out) {
    __shared__ float At[CC_BK][CC_BM + 4];
    __shared__ float Bt[CC_BK][CC_BN];

    const int t    = threadIdx.x;
    const int row0 = blockIdx.x * CC_BM;
    const int col0 = blockIdx.y * CC_BN;
    const int tx   = t & 15;
    const int ty   = t >> 4;

    float acc[8][8];
#pragma unroll
    for (int i = 0; i < 8; ++i)
#pragma unroll
        for (int j = 0; j < 8; ++j) acc[i][j] = 0.f;

    for (int k0 = 0; k0 < C_; k0 += CC_BK) {
        {
            int k4 = (t & 3) * 4;
            int ra = t >> 2;   // 0..63
#pragma unroll
            for (int rr = 0; rr < 2; ++rr) {
                int r = ra + rr * 64;
                float4 q = *(const float4*)&A[(size_t)(row0 + r) * C_ + k0 + k4];
                At[k4 + 0][r] = q.x;
                At[k4 + 1][r] = q.y;
                At[k4 + 2][r] = q.z;
                At[k4 + 3][r] = q.w;
            }
        }
        {
            int c4 = (t & 31) * 4;
            int kb = t >> 5;   // 0..7
#pragma unroll
            for (int i = 0; i < 2; ++i) {
                int k = kb + i * 8;
                *(float4*)&Bt[k][c4] = *(const float4*)&Bm[(size_t)(k0 + k) * C_ + col0 + c4];
            }
        }
        __syncthreads();

#pragma unroll
        for (int k = 0; k < CC_BK; ++k) {
            float4 a0 = *(const float4*)&At[k][ty * 8];
            float4 a1 = *(const float4*)&At[k][ty * 8 + 4];
            float4 b0 = *(const float4*)&Bt[k][tx * 8];
            float4 b1 = *(const float4*)&Bt[k][tx * 8 + 4];
            float av[8] = {a0.x, a0.y, a0.z, a0.w, a1.x, a1.y, a1.z, a1.w};
            float bv[8] = {b0.x, b0.y, b0.z, b0.w, b1.x, b1.y, b1.z, b1.w};
#pragma unroll
            for (int i = 0; i < 8; ++i)
#pragma unroll
                for (int j = 0; j < 8; ++j) acc[i][j] += av[i] * bv[j];
        }
        __syncthreads();
    }

#pragma unroll
    for (int i = 0; i < 8; ++i) {
        size_t row = (size_t)(row0 + ty * 8 + i);
#pragma unroll
        for (int j = 0; j < 8; j += 4) {
            int col = col0 + tx * 8 + j;
            float4 o = make_float4(acc[i][j + 0] + bias[col + 0],
                                   acc[i][j + 1] + bias[col + 1],
                                   acc[i][j + 2] + bias[col + 2],
                                   acc[i][j + 3] + bias[col + 3]);
            *(float4*)&out[row * C_ + col] = o;
        }
    }
}

// ---------------------------------------------------------------------------
// launcher
// ws layout: val   [0,               134217728)  : B*8*HW*32 f32
//            locattn [134217728,     167772160)  : B*N*8*4 float4
//            mid   [167772160,       234881024)  : B*N*256 f32
// ---------------------------------------------------------------------------
extern "C" void kernel_launch(void* const* d_in, const int* in_sizes, int n_in,
                              void* d_out, int out_size, void* d_ws, size_t ws_size,
                              hipStream_t stream) {
    const float* query  = (const float*)d_in[0];
    const float* refp   = (const float*)d_in[1];
    const float* value  = (const float*)d_in[2];
    const float* W_off  = (const float*)d_in[3];
    const float* b_off  = (const float*)d_in[4];
    const float* W_attn = (const float*)d_in[5];
    const float* b_attn = (const float*)d_in[6];
    const float* W_out  = (const float*)d_in[7];
    const float* b_out  = (const float*)d_in[8];
    float* out = (float*)d_out;

    char*   ws      = (char*)d_ws;
    float*  val     = (float*)(ws);
    float4* locattn = (float4*)(ws + 134217728);
    float*  mid     = (float*)(ws + 167772160);

    kT <<<dim3(HW / 64, B_ * HH), 256, 0, stream>>>(value, val);
    kA1<<<dim3((B_ * N_) / A1_BM), 256, 0, stream>>>(query, refp, W_off, b_off,
                                                     W_attn, b_attn, locattn);
    kA2<<<dim3(N_ / 8, B_ * HH), 256, 0, stream>>>(locattn, val, mid);
    kC <<<dim3((B_ * N_) / CC_BM, C_ / CC_BN), 256, 0, stream>>>(mid, W_out, b_out, out);
}

// Round 2
// 449.350 us; speedup vs baseline: 1.2116x; 1.2116x over previous
//
#include <hip/hip_runtime.h>
#include <hip/hip_bf16.h>
#include <cstddef>

#define B_  8
#define N_  8192
#define C_  256
#define H_  128
#define W_  128
#define HH  8
#define PP  4
#define DD  32
#define HW  (H_ * W_)

typedef short bf16x8 __attribute__((ext_vector_type(8)));
typedef float f32x4  __attribute__((ext_vector_type(4)));

// ---------------------------------------------------------------------------
// kT: transpose value (B, C=256, H, W) -> val (B*8, H*W, 32)
// ---------------------------------------------------------------------------
__global__ __launch_bounds__(256) void kT(const float* __restrict__ value,
                                          float* __restrict__ val) {
    __shared__ float tile[32][65];
    const int bh   = blockIdx.y;
    const int pix0 = blockIdx.x * 64;
    const int t    = threadIdx.x;

    const float* src = value + (size_t)bh * 32 * HW + pix0;
#pragma unroll
    for (int i = 0; i < 8; ++i) {
        int d = i * 4 + (t >> 6);
        int p = t & 63;
        tile[d][p] = src[(size_t)d * HW + p];
    }
    __syncthreads();
    float* dst = val + ((size_t)bh * HW + pix0) * 32;
#pragma unroll
    for (int j = 0; j < 8; ++j) {
        int p = j * 8 + (t >> 5);
        int d = t & 31;
        dst[(size_t)p * 32 + d] = tile[d][p];
    }
}

// ---------------------------------------------------------------------------
// kA1: offset/attn GEMM (65536x256)@(256x96) + bias + softmax + loc epilogue
// ---------------------------------------------------------------------------
#define A1_BM 128
#define A1_BK 32

__global__ __launch_bounds__(256) void kA1(const float* __restrict__ query,
                                           const float* __restrict__ refp,
                                           const float* __restrict__ W_off,
                                           const float* __restrict__ b_off,
                                           const float* __restrict__ W_attn,
                                           const float* __restrict__ b_attn,
                                           float4* __restrict__ locattn) {
    __shared__ float At[A1_BK][A1_BM + 4];
    __shared__ float Bo[A1_BK][64];
    __shared__ float Ba[A1_BK][32];

    const int t    = threadIdx.x;
    const int row0 = blockIdx.x * A1_BM;
    const int rg   = t >> 3;
    const int h    = t & 7;

    float accO[4][8];
    float accA[4][4];
#pragma unroll
    for (int r = 0; r < 4; ++r) {
#pragma unroll
        for (int j = 0; j < 8; ++j) accO[r][j] = 0.f;
#pragma unroll
        for (int j = 0; j < 4; ++j) accA[r][j] = 0.f;
    }

    for (int k0 = 0; k0 < C_; k0 += A1_BK) {
        {
            int kq = (t & 7) * 4;
            int ra = t >> 3;
#pragma unroll
            for (int rr = 0; rr < 4; ++rr) {
                int r = ra + rr * 32;
                float4 q = *(const float4*)&query[(size_t)(row0 + r) * C_ + k0 + kq];
                At[kq + 0][r] = q.x;
                At[kq + 1][r] = q.y;
                At[kq + 2][r] = q.z;
                At[kq + 3][r] = q.w;
            }
        }
        {
            int c4 = (t & 15) * 4;
            int kb = t >> 4;
#pragma unroll
            for (int i = 0; i < 2; ++i) {
                int k = kb + i * 16;
                *(float4*)&Bo[k][c4] = *(const float4*)&W_off[(size_t)(k0 + k) * 64 + c4];
            }
        }
        {
            int c4 = (t & 7) * 4;
            int kb = t >> 3;
            *(float4*)&Ba[kb][c4] = *(const float4*)&W_attn[(size_t)(k0 + kb) * 32 + c4];
        }
        __syncthreads();

#pragma unroll
        for (int k = 0; k < A1_BK; ++k) {
            float4 a   = *(const float4*)&At[k][rg * 4];
            float4 bo0 = *(const float4*)&Bo[k][h * 8];
            float4 bo1 = *(const float4*)&Bo[k][h * 8 + 4];
            float4 ba  = *(const float4*)&Ba[k][h * 4];
            float av[4] = {a.x, a.y, a.z, a.w};
            float bO[8] = {bo0.x, bo0.y, bo0.z, bo0.w, bo1.x, bo1.y, bo1.z, bo1.w};
            float bA[4] = {ba.x, ba.y, ba.z, ba.w};
#pragma unroll
            for (int r = 0; r < 4; ++r) {
#pragma unroll
                for (int j = 0; j < 8; ++j) accO[r][j] += av[r] * bO[j];
#pragma unroll
                for (int j = 0; j < 4; ++j) accA[r][j] += av[r] * bA[j];
            }
        }
        __syncthreads();
    }

    float boff[8];
#pragma unroll
    for (int j = 0; j < 8; ++j) boff[j] = b_off[h * 8 + j];
    float batn[4];
#pragma unroll
    for (int j = 0; j < 4; ++j) batn[j] = b_attn[h * 4 + j];

#pragma unroll
    for (int r = 0; r < 4; ++r) {
        int row  = row0 + rg * 4 + r;
        float rx = refp[(size_t)row * 2 + 0];
        float ry = refp[(size_t)row * 2 + 1];
        float lg[4];
#pragma unroll
        for (int p = 0; p < 4; ++p) lg[p] = accA[r][p] + batn[p];
        float m = fmaxf(fmaxf(lg[0], lg[1]), fmaxf(lg[2], lg[3]));
        float e[4];
        float s = 0.f;
#pragma unroll
        for (int p = 0; p < 4; ++p) { e[p] = __expf(lg[p] - m); s += e[p]; }
        float inv = 1.f / s;
#pragma unroll
        for (int p = 0; p < 4; ++p) {
            float ox = accO[r][p * 2 + 0] + boff[p * 2 + 0];
            float oy = accO[r][p * 2 + 1] + boff[p * 2 + 1];
            float x  = (rx * 2.f + ox) * (W_ * 0.5f) - 0.5f;
            float y  = (ry * 2.f + oy) * (H_ * 0.5f) - 0.5f;
            locattn[((size_t)row * HH + h) * PP + p] = make_float4(x, y, e[p] * inv, 0.f);
        }
    }
}

// ---------------------------------------------------------------------------
// kA2: bilinear sampling + attention weighting -> mid (B*N, 256) in bf16
// ---------------------------------------------------------------------------
__global__ __launch_bounds__(256) void kA2(const float4* __restrict__ locattn,
                                           const float* __restrict__ val,
                                           __hip_bfloat16* __restrict__ mid) {
    const int t  = threadIdx.x;
    const int d  = t & 31;
    const int lr = t >> 5;
    const int bh = blockIdx.y;
    const int b  = bh >> 3;
    const int h  = bh & 7;
    const int n  = blockIdx.x * 8 + lr;
    const size_t row = (size_t)b * N_ + n;

    const float4* la    = &locattn[(row * HH + h) * PP];
    const float*  vbase = val + (size_t)bh * HW * DD + d;

    float acc = 0.f;
#pragma unroll
    for (int p = 0; p < PP; ++p) {
        float4 L = la[p];
        float x = L.x, y = L.y, a = L.z;
        float xf = floorf(x), yf = floorf(y);
        int x0 = (int)xf, y0 = (int)yf;
        int x1 = x0 + 1, y1 = y0 + 1;
        float wx1 = x - xf, wy1 = y - yf;
        float wx0 = 1.f - wx1, wy0 = 1.f - wy1;
        int cx0 = min(max(x0, 0), W_ - 1);
        int cx1 = min(max(x1, 0), W_ - 1);
        int cy0 = min(max(y0, 0), H_ - 1);
        int cy1 = min(max(y1, 0), H_ - 1);
        float m00 = (x0 >= 0 && x0 < W_ && y0 >= 0 && y0 < H_) ? 1.f : 0.f;
        float m10 = (x1 >= 0 && x1 < W_ && y0 >= 0 && y0 < H_) ? 1.f : 0.f;
        float m01 = (x0 >= 0 && x0 < W_ && y1 >= 0 && y1 < H_) ? 1.f : 0.f;
        float m11 = (x1 >= 0 && x1 < W_ && y1 >= 0 && y1 < H_) ? 1.f : 0.f;
        float v00 = vbase[((size_t)(cy0 * W_ + cx0)) * DD];
        float v10 = vbase[((size_t)(cy0 * W_ + cx1)) * DD];
        float v01 = vbase[((size_t)(cy1 * W_ + cx0)) * DD];
        float v11 = vbase[((size_t)(cy1 * W_ + cx1)) * DD];
        acc += a * (v00 * (wx0 * wy0 * m00) + v10 * (wx1 * wy0 * m10) +
                    v01 * (wx0 * wy1 * m01) + v11 * (wx1 * wy1 * m11));
    }
    mid[row * C_ + h * DD + d] = __float2bfloat16(acc);
}

// ---------------------------------------------------------------------------
// kW: W_out (256x256 f32, k-major) -> Wt (256x256 bf16, n-major)
// ---------------------------------------------------------------------------
__global__ __launch_bounds__(256) void kW(const float* __restrict__ Wsrc,
                                          __hip_bfloat16* __restrict__ Wt) {
    __shared__ float tile[64][65];
    const int n0 = blockIdx.x * 64;
    const int k0 = blockIdx.y * 64;
    const int t  = threadIdx.x;
#pragma unroll
    for (int i = 0; i < 16; ++i) {
        int kk = i * 4 + (t >> 6);
        int nn = t & 63;
        tile[kk][nn] = Wsrc[(size_t)(k0 + kk) * 256 + n0 + nn];
    }
    __syncthreads();
#pragma unroll
    for (int i = 0; i < 16; ++i) {
        int nn = i * 4 + (t >> 6);
        int kk = t & 63;
        Wt[(size_t)(n0 + nn) * 256 + k0 + kk] = __float2bfloat16(tile[kk][nn]);
    }
}

// ---------------------------------------------------------------------------
// kC: out = mid (65536x256 bf16) @ Wt^T (Wt is n-major 256x256 bf16) + bias
// 128x128 tile, BK=64, 4 waves (2x2 of 64x64), mfma_f32_16x16x32_bf16.
// LDS XOR-swizzle: 8-elem k-block index ^= (row & 7) -> <=2-way bank alias.
// ---------------------------------------------------------------------------
__global__ __launch_bounds__(256) void kC(const short* __restrict__ mid,
                                          const short* __restrict__ Wt,
                                          const float* __restrict__ bias,
                                          float* __restrict__ out) {
    __shared__ __align__(16) short As[128 * 64];
    __shared__ __align__(16) short Bs[128 * 64];

    const int t    = threadIdx.x;
    const int lane = t & 63;
    const int w    = t >> 6;
    const int wm   = (w & 1) * 64;
    const int wn   = (w >> 1) * 64;
    const int row0 = blockIdx.x * 128;
    const int col0 = blockIdx.y * 128;

    f32x4 acc[4][4];
#pragma unroll
    for (int mt = 0; mt < 4; ++mt)
#pragma unroll
        for (int nt = 0; nt < 4; ++nt)
            acc[mt][nt] = (f32x4){0.f, 0.f, 0.f, 0.f};

    const int sr = t >> 3;   // 0..31 staging row
    const int kb = t & 7;    // 0..7  staging 8-elem k-block

    for (int k0 = 0; k0 < 4; ++k0) {
#pragma unroll
        for (int i = 0; i < 4; ++i) {
            int row  = sr + i * 32;
            int kbs  = (kb ^ (row & 7)) * 8;
            *(uint4*)&As[row * 64 + kbs] =
                *(const uint4*)&mid[(size_t)(row0 + row) * 256 + k0 * 64 + kb * 8];
            *(uint4*)&Bs[row * 64 + kbs] =
                *(const uint4*)&Wt[(size_t)(col0 + row) * 256 + k0 * 64 + kb * 8];
        }
        __syncthreads();

#pragma unroll
        for (int ks = 0; ks < 2; ++ks) {
            const int kq = ks * 4 + (lane >> 4);   // 8-elem block idx 0..7
            bf16x8 af[4], bf[4];
#pragma unroll
            for (int mt = 0; mt < 4; ++mt) {
                int m = wm + mt * 16 + (lane & 15);
                af[mt] = *(const bf16x8*)&As[m * 64 + (kq ^ (m & 7)) * 8];
            }
#pragma unroll
            for (int nt = 0; nt < 4; ++nt) {
                int n = wn + nt * 16 + (lane & 15);
                bf[nt] = *(const bf16x8*)&Bs[n * 64 + (kq ^ (n & 7)) * 8];
            }
#pragma unroll
            for (int mt = 0; mt < 4; ++mt)
#pragma unroll
                for (int nt = 0; nt < 4; ++nt)
                    acc[mt][nt] = __builtin_amdgcn_mfma_f32_16x16x32_bf16(
                        af[mt], bf[nt], acc[mt][nt], 0, 0, 0);
        }
        __syncthreads();
    }

    const int cq = lane >> 4;
#pragma unroll
    for (int nt = 0; nt < 4; ++nt) {
        int col  = col0 + wn + nt * 16 + (lane & 15);
        float bv = bias[col];
#pragma unroll
        for (int mt = 0; mt < 4; ++mt) {
#pragma unroll
            for (int rI = 0; rI < 4; ++rI) {
                int rowg = row0 + wm + mt * 16 + cq * 4 + rI;
                out[(size_t)rowg * 256 + col] = acc[mt][nt][rI] + bv;
            }
        }
    }
}

// ---------------------------------------------------------------------------
// launcher
// ws: val     [0,         134217728)  B*8*HW*32 f32
//     locattn [134217728, 167772160)  B*N*8*4 float4
//     mid     [167772160, 201326592)  B*N*256 bf16
//     Wt      [201326592, 201457664)  256*256 bf16
// ---------------------------------------------------------------------------
extern "C" void kernel_launch(void* const* d_in, const int* in_sizes, int n_in,
                              void* d_out, int out_size, void* d_ws, size_t ws_size,
                              hipStream_t stream) {
    const float* query  = (const float*)d_in[0];
    const float* refp   = (const float*)d_in[1];
    const float* value  = (const float*)d_in[2];
    const float* W_off  = (const float*)d_in[3];
    const float* b_off  = (const float*)d_in[4];
    const float* W_attn = (const float*)d_in[5];
    const float* b_attn = (const float*)d_in[6];
    const float* W_out  = (const float*)d_in[7];
    const float* b_out  = (const float*)d_in[8];
    float* out = (float*)d_out;

    char*           ws      = (char*)d_ws;
    float*          val     = (float*)(ws);
    float4*         locattn = (float4*)(ws + 134217728);
    __hip_bfloat16* mid     = (__hip_bfloat16*)(ws + 167772160);
    __hip_bfloat16* Wt      = (__hip_bfloat16*)(ws + 201326592);

    kT <<<dim3(HW / 64, B_ * HH), 256, 0, stream>>>(value, val);
    kW <<<dim3(4, 4), 256, 0, stream>>>(W_out, Wt);
    kA1<<<dim3((B_ * N_) / A1_BM), 256, 0, stream>>>(query, refp, W_off, b_off,
                                                     W_attn, b_attn, locattn);
    kA2<<<dim3(N_ / 8, B_ * HH), 256, 0, stream>>>(locattn, val, mid);
    kC <<<dim3((B_ * N_) / 128, C_ / 128), 256, 0, stream>>>(
        (const short*)mid, (const short*)Wt, b_out, out);
}

// Round 3
// 395.804 us; speedup vs baseline: 1.3756x; 1.1353x over previous
//
#include <hip/hip_runtime.h>
#include <hip/hip_bf16.h>
#include <cstddef>

#define B_  8
#define N_  8192
#define C_  256
#define H_  128
#define W_  128
#define HH  8
#define PP  4
#define DD  32
#define HW  (H_ * W_)

typedef short bf16x8 __attribute__((ext_vector_type(8)));
typedef float f32x4  __attribute__((ext_vector_type(4)));

// ---------------------------------------------------------------------------
// kT: transpose value (B, C=256, H, W) -> val (B*8, H*W, 32) in bf16
// ---------------------------------------------------------------------------
__global__ __launch_bounds__(256) void kT(const float* __restrict__ value,
                                          __hip_bfloat16* __restrict__ val) {
    __shared__ float tile[32][65];
    const int bh   = blockIdx.y;
    const int pix0 = blockIdx.x * 64;
    const int t    = threadIdx.x;

    const float* src = value + (size_t)bh * 32 * HW + pix0;
#pragma unroll
    for (int i = 0; i < 8; ++i) {
        int d = i * 4 + (t >> 6);
        int p = t & 63;
        tile[d][p] = src[(size_t)d * HW + p];
    }
    __syncthreads();
    __hip_bfloat162* dst =
        (__hip_bfloat162*)(val + ((size_t)bh * HW + pix0) * 32);
#pragma unroll
    for (int j = 0; j < 4; ++j) {
        int p  = j * 16 + (t >> 4);
        int dd = (t & 15) * 2;
        __hip_bfloat162 pk;
        pk.x = __float2bfloat16(tile[dd][p]);
        pk.y = __float2bfloat16(tile[dd + 1][p]);
        dst[p * 16 + (t & 15)] = pk;
    }
}

// ---------------------------------------------------------------------------
// kA1: offset/attn GEMM (65536x256)@(256x96) + bias + softmax + loc epilogue
// writes locattn in [bh][n][p] layout (h-major) for kA2 contiguity
// ---------------------------------------------------------------------------
#define A1_BM 128
#define A1_BK 32

__global__ __launch_bounds__(256) void kA1(const float* __restrict__ query,
                                           const float* __restrict__ refp,
                                           const float* __restrict__ W_off,
                                           const float* __restrict__ b_off,
                                           const float* __restrict__ W_attn,
                                           const float* __restrict__ b_attn,
                                           float4* __restrict__ locattn) {
    __shared__ float At[A1_BK][A1_BM + 4];
    __shared__ float Bo[A1_BK][64];
    __shared__ float Ba[A1_BK][32];

    const int t    = threadIdx.x;
    const int row0 = blockIdx.x * A1_BM;
    const int rg   = t >> 3;
    const int h    = t & 7;

    float accO[4][8];
    float accA[4][4];
#pragma unroll
    for (int r = 0; r < 4; ++r) {
#pragma unroll
        for (int j = 0; j < 8; ++j) accO[r][j] = 0.f;
#pragma unroll
        for (int j = 0; j < 4; ++j) accA[r][j] = 0.f;
    }

    for (int k0 = 0; k0 < C_; k0 += A1_BK) {
        {
            int kq = (t & 7) * 4;
            int ra = t >> 3;
#pragma unroll
            for (int rr = 0; rr < 4; ++rr) {
                int r = ra + rr * 32;
                float4 q = *(const float4*)&query[(size_t)(row0 + r) * C_ + k0 + kq];
                At[kq + 0][r] = q.x;
                At[kq + 1][r] = q.y;
                At[kq + 2][r] = q.z;
                At[kq + 3][r] = q.w;
            }
        }
        {
            int c4 = (t & 15) * 4;
            int kb = t >> 4;
#pragma unroll
            for (int i = 0; i < 2; ++i) {
                int k = kb + i * 16;
                *(float4*)&Bo[k][c4] = *(const float4*)&W_off[(size_t)(k0 + k) * 64 + c4];
            }
        }
        {
            int c4 = (t & 7) * 4;
            int kb = t >> 3;
            *(float4*)&Ba[kb][c4] = *(const float4*)&W_attn[(size_t)(k0 + kb) * 32 + c4];
        }
        __syncthreads();

#pragma unroll
        for (int k = 0; k < A1_BK; ++k) {
            float4 a   = *(const float4*)&At[k][rg * 4];
            float4 bo0 = *(const float4*)&Bo[k][h * 8];
            float4 bo1 = *(const float4*)&Bo[k][h * 8 + 4];
            float4 ba  = *(const float4*)&Ba[k][h * 4];
            float av[4] = {a.x, a.y, a.z, a.w};
            float bO[8] = {bo0.x, bo0.y, bo0.z, bo0.w, bo1.x, bo1.y, bo1.z, bo1.w};
            float bA[4] = {ba.x, ba.y, ba.z, ba.w};
#pragma unroll
            for (int r = 0; r < 4; ++r) {
#pragma unroll
                for (int j = 0; j < 8; ++j) accO[r][j] += av[r] * bO[j];
#pragma unroll
                for (int j = 0; j < 4; ++j) accA[r][j] += av[r] * bA[j];
            }
        }
        __syncthreads();
    }

    float boff[8];
#pragma unroll
    for (int j = 0; j < 8; ++j) boff[j] = b_off[h * 8 + j];
    float batn[4];
#pragma unroll
    for (int j = 0; j < 4; ++j) batn[j] = b_attn[h * 4 + j];

#pragma unroll
    for (int r = 0; r < 4; ++r) {
        int row  = row0 + rg * 4 + r;
        int bb   = row >> 13;
        int nn   = row & 8191;
        float rx = refp[(size_t)row * 2 + 0];
        float ry = refp[(size_t)row * 2 + 1];
        float lg[4];
#pragma unroll
        for (int p = 0; p < 4; ++p) lg[p] = accA[r][p] + batn[p];
        float m = fmaxf(fmaxf(lg[0], lg[1]), fmaxf(lg[2], lg[3]));
        float e[4];
        float s = 0.f;
#pragma unroll
        for (int p = 0; p < 4; ++p) { e[p] = __expf(lg[p] - m); s += e[p]; }
        float inv = 1.f / s;
#pragma unroll
        for (int p = 0; p < 4; ++p) {
            float ox = accO[r][p * 2 + 0] + boff[p * 2 + 0];
            float oy = accO[r][p * 2 + 1] + boff[p * 2 + 1];
            float x  = (rx * 2.f + ox) * (W_ * 0.5f) - 0.5f;
            float y  = (ry * 2.f + oy) * (H_ * 0.5f) - 0.5f;
            locattn[(((size_t)bb * HH + h) * N_ + nn) * PP + p] =
                make_float4(x, y, e[p] * inv, 0.f);
        }
    }
}

// ---------------------------------------------------------------------------
// kA2: bilinear sampling + attention weighting -> mid (B*N, 256) bf16
// Phase 1: 1 thread per (row,point) computes 4 corner offsets + premultiplied
//          weights into LDS. Phase 2: broadcast ds_read_b128 + gather + FMA.
// block = 64 rows of one bh; grid (N/64, B*8).
// ---------------------------------------------------------------------------
__global__ __launch_bounds__(256) void kA2(const float4* __restrict__ locattn,
                                           const __hip_bfloat16* __restrict__ val,
                                           __hip_bfloat16* __restrict__ mid) {
    __shared__ float2 ow[64][4][4];   // [row][point][corner] = (off_as_int, w)

    const int t  = threadIdx.x;
    const int bh = blockIdx.y;
    const int b  = bh >> 3;
    const int h  = bh & 7;
    const int n0 = blockIdx.x * 64;

    // ---- phase 1 ----
    {
        const int r = t >> 2;
        const int p = t & 3;
        float4 L = locattn[((size_t)bh * N_ + n0 + r) * PP + p];
        float x = L.x, y = L.y, a = L.z;
        float xf = floorf(x), yf = floorf(y);
        int x0 = (int)xf, y0 = (int)yf;
        int x1 = x0 + 1, y1 = y0 + 1;
        float wx1 = x - xf, wy1 = y - yf;
        float wx0 = 1.f - wx1, wy0 = 1.f - wy1;
        int cx0 = min(max(x0, 0), W_ - 1);
        int cx1 = min(max(x1, 0), W_ - 1);
        int cy0 = min(max(y0, 0), H_ - 1);
        int cy1 = min(max(y1, 0), H_ - 1);
        bool bx0 = (x0 >= 0) & (x0 < W_);
        bool bx1 = (x1 >= 0) & (x1 < W_);
        bool by0 = (y0 >= 0) & (y0 < H_);
        bool by1 = (y1 >= 0) & (y1 < H_);
        float w00 = a * wx0 * wy0 * ((bx0 & by0) ? 1.f : 0.f);
        float w10 = a * wx1 * wy0 * ((bx1 & by0) ? 1.f : 0.f);
        float w01 = a * wx0 * wy1 * ((bx0 & by1) ? 1.f : 0.f);
        float w11 = a * wx1 * wy1 * ((bx1 & by1) ? 1.f : 0.f);
        ow[r][p][0] = make_float2(__int_as_float(cy0 * W_ + cx0), w00);
        ow[r][p][1] = make_float2(__int_as_float(cy0 * W_ + cx1), w10);
        ow[r][p][2] = make_float2(__int_as_float(cy1 * W_ + cx0), w01);
        ow[r][p][3] = make_float2(__int_as_float(cy1 * W_ + cx1), w11);
    }
    __syncthreads();

    // ---- phase 2 ----
    const int d  = t & 31;
    const int rg = t >> 5;
    const __hip_bfloat16* vb = val + (size_t)bh * HW * DD + d;
    __hip_bfloat16* mo = mid + ((size_t)b * N_ + n0) * C_ + h * DD + d;

#pragma unroll
    for (int j = 0; j < 8; ++j) {
        int r = rg * 8 + j;
        const float4* owp = (const float4*)&ow[r][0][0];
        float acc = 0.f;
#pragma unroll
        for (int p = 0; p < 4; ++p) {
            float4 u0 = owp[p * 2 + 0];
            float4 u1 = owp[p * 2 + 1];
            int o00 = __float_as_int(u0.x) * DD;
            int o10 = __float_as_int(u0.z) * DD;
            int o01 = __float_as_int(u1.x) * DD;
            int o11 = __float_as_int(u1.z) * DD;
            acc += u0.y * __bfloat162float(vb[o00]);
            acc += u0.w * __bfloat162float(vb[o10]);
            acc += u1.y * __bfloat162float(vb[o01]);
            acc += u1.w * __bfloat162float(vb[o11]);
        }
        mo[r * C_] = __float2bfloat16(acc);
    }
}

// ---------------------------------------------------------------------------
// kW: W_out (256x256 f32, k-major) -> Wt (256x256 bf16, n-major)
// ---------------------------------------------------------------------------
__global__ __launch_bounds__(256) void kW(const float* __restrict__ Wsrc,
                                          __hip_bfloat16* __restrict__ Wt) {
    __shared__ float tile[64][65];
    const int n0 = blockIdx.x * 64;
    const int k0 = blockIdx.y * 64;
    const int t  = threadIdx.x;
#pragma unroll
    for (int i = 0; i < 16; ++i) {
        int kk = i * 4 + (t >> 6);
        int nn = t & 63;
        tile[kk][nn] = Wsrc[(size_t)(k0 + kk) * 256 + n0 + nn];
    }
    __syncthreads();
#pragma unroll
    for (int i = 0; i < 16; ++i) {
        int nn = i * 4 + (t >> 6);
        int kk = t & 63;
        Wt[(size_t)(n0 + nn) * 256 + k0 + kk] = __float2bfloat16(tile[kk][nn]);
    }
}

// ---------------------------------------------------------------------------
// kC: out = mid (65536x256 bf16) @ Wt^T (n-major bf16) + bias, MFMA
// ---------------------------------------------------------------------------
__global__ __launch_bounds__(256) void kC(const short* __restrict__ mid,
                                          const short* __restrict__ Wt,
                                          const float* __restrict__ bias,
                                          float* __restrict__ out) {
    __shared__ __align__(16) short As[128 * 64];
    __shared__ __align__(16) short Bs[128 * 64];

    const int t    = threadIdx.x;
    const int lane = t & 63;
    const int w    = t >> 6;
    const int wm   = (w & 1) * 64;
    const int wn   = (w >> 1) * 64;
    const int row0 = blockIdx.x * 128;
    const int col0 = blockIdx.y * 128;

    f32x4 acc[4][4];
#pragma unroll
    for (int mt = 0; mt < 4; ++mt)
#pragma unroll
        for (int nt = 0; nt < 4; ++nt)
            acc[mt][nt] = (f32x4){0.f, 0.f, 0.f, 0.f};

    const int sr = t >> 3;
    const int kb = t & 7;

    for (int k0 = 0; k0 < 4; ++k0) {
#pragma unroll
        for (int i = 0; i < 4; ++i) {
            int row  = sr + i * 32;
            int kbs  = (kb ^ (row & 7)) * 8;
            *(uint4*)&As[row * 64 + kbs] =
                *(const uint4*)&mid[(size_t)(row0 + row) * 256 + k0 * 64 + kb * 8];
            *(uint4*)&Bs[row * 64 + kbs] =
                *(const uint4*)&Wt[(size_t)(col0 + row) * 256 + k0 * 64 + kb * 8];
        }
        __syncthreads();

#pragma unroll
        for (int ks = 0; ks < 2; ++ks) {
            const int kq = ks * 4 + (lane >> 4);
            bf16x8 af[4], bf[4];
#pragma unroll
            for (int mt = 0; mt < 4; ++mt) {
                int m = wm + mt * 16 + (lane & 15);
                af[mt] = *(const bf16x8*)&As[m * 64 + (kq ^ (m & 7)) * 8];
            }
#pragma unroll
            for (int nt = 0; nt < 4; ++nt) {
                int n = wn + nt * 16 + (lane & 15);
                bf[nt] = *(const bf16x8*)&Bs[n * 64 + (kq ^ (n & 7)) * 8];
            }
#pragma unroll
            for (int mt = 0; mt < 4; ++mt)
#pragma unroll
                for (int nt = 0; nt < 4; ++nt)
                    acc[mt][nt] = __builtin_amdgcn_mfma_f32_16x16x32_bf16(
                        af[mt], bf[nt], acc[mt][nt], 0, 0, 0);
        }
        __syncthreads();
    }

    const int cq = lane >> 4;
#pragma unroll
    for (int nt = 0; nt < 4; ++nt) {
        int col  = col0 + wn + nt * 16 + (lane & 15);
        float bv = bias[col];
#pragma unroll
        for (int mt = 0; mt < 4; ++mt) {
#pragma unroll
            for (int rI = 0; rI < 4; ++rI) {
                int rowg = row0 + wm + mt * 16 + cq * 4 + rI;
                out[(size_t)rowg * 256 + col] = acc[mt][nt][rI] + bv;
            }
        }
    }
}

// ---------------------------------------------------------------------------
// launcher
// ws: val     [0,          67108864)  B*8*HW*32 bf16
//     locattn [67108864,  100663296)  B*8*N*4 float4  (bh-major)
//     mid     [100663296, 134217728)  B*N*256 bf16
//     Wt      [134217728, 134348800)  256*256 bf16
// ---------------------------------------------------------------------------
extern "C" void kernel_launch(void* const* d_in, const int* in_sizes, int n_in,
                              void* d_out, int out_size, void* d_ws, size_t ws_size,
                              hipStream_t stream) {
    const float* query  = (const float*)d_in[0];
    const float* refp   = (const float*)d_in[1];
    const float* value  = (const float*)d_in[2];
    const float* W_off  = (const float*)d_in[3];
    const float* b_off  = (const float*)d_in[4];
    const float* W_attn = (const float*)d_in[5];
    const float* b_attn = (const float*)d_in[6];
    const float* W_out  = (const float*)d_in[7];
    const float* b_out  = (const float*)d_in[8];
    float* out = (float*)d_out;

    char*           ws      = (char*)d_ws;
    __hip_bfloat16* val     = (__hip_bfloat16*)(ws);
    float4*         locattn = (float4*)(ws + 67108864);
    __hip_bfloat16* mid     = (__hip_bfloat16*)(ws + 100663296);
    __hip_bfloat16* Wt      = (__hip_bfloat16*)(ws + 134217728);

    kT <<<dim3(HW / 64, B_ * HH), 256, 0, stream>>>(value, val);
    kW <<<dim3(4, 4), 256, 0, stream>>>(W_out, Wt);
    kA1<<<dim3((B_ * N_) / A1_BM), 256, 0, stream>>>(query, refp, W_off, b_off,
                                                     W_attn, b_attn, locattn);
    kA2<<<dim3(N_ / 64, B_ * HH), 256, 0, stream>>>(locattn, val, mid);
    kC <<<dim3((B_ * N_) / 128, C_ / 128), 256, 0, stream>>>(
        (const short*)mid, (const short*)Wt, b_out, out);
}

// Round 4
// 381.298 us; speedup vs baseline: 1.4279x; 1.0380x over previous
//
#include <hip/hip_runtime.h>
#include <hip/hip_bf16.h>
#include <cstddef>

#define B_  8
#define N_  8192
#define C_  256
#define H_  128
#define W_  128
#define HH  8
#define PP  4
#define DD  32
#define HW  (H_ * W_)

typedef short bf16x8 __attribute__((ext_vector_type(8)));
typedef float f32x4  __attribute__((ext_vector_type(4)));

static __device__ __forceinline__ short f2bf_s(float f) {
    __hip_bfloat16 b = __float2bfloat16(f);
    return *reinterpret_cast<short*>(&b);
}
static __device__ __forceinline__ float bf_s2f(short s) {
    __hip_bfloat16 b = *reinterpret_cast<__hip_bfloat16*>(&s);
    return __bfloat162float(b);
}

// ---------------------------------------------------------------------------
// kT: transpose value (B, C=256, H, W) -> val (B*8, H*W, 32) in bf16
// ---------------------------------------------------------------------------
__global__ __launch_bounds__(256) void kT(const float* __restrict__ value,
                                          __hip_bfloat16* __restrict__ val) {
    __shared__ float tile[32][65];
    const int bh   = blockIdx.y;
    const int pix0 = blockIdx.x * 64;
    const int t    = threadIdx.x;

    const float* src = value + (size_t)bh * 32 * HW + pix0;
#pragma unroll
    for (int i = 0; i < 8; ++i) {
        int d = i * 4 + (t >> 6);
        int p = t & 63;
        tile[d][p] = src[(size_t)d * HW + p];
    }
    __syncthreads();
    __hip_bfloat162* dst =
        (__hip_bfloat162*)(val + ((size_t)bh * HW + pix0) * 32);
#pragma unroll
    for (int j = 0; j < 4; ++j) {
        int p  = j * 16 + (t >> 4);
        int dd = (t & 15) * 2;
        __hip_bfloat162 pk;
        pk.x = __float2bfloat16(tile[dd][p]);
        pk.y = __float2bfloat16(tile[dd + 1][p]);
        dst[p * 16 + (t & 15)] = pk;
    }
}

// ---------------------------------------------------------------------------
// kP: split W_off (256x64) + W_attn (256x32) -> Wc_hi/Wc_lo (96x256 bf16,
// n-major).  Combined col c: c<64 -> W_off[:,c]; else W_attn[:,c-64].
// ---------------------------------------------------------------------------
__global__ __launch_bounds__(256) void kP(const float* __restrict__ W_off,
                                          const float* __restrict__ W_attn,
                                          short* __restrict__ Wc_hi,
                                          short* __restrict__ Wc_lo) {
    const int c = blockIdx.x;
    const int k = threadIdx.x;
    float v = (c < 64) ? W_off[(size_t)k * 64 + c]
                       : W_attn[(size_t)k * 32 + (c - 64)];
    short h = f2bf_s(v);
    short l = f2bf_s(v - bf_s2f(h));
    Wc_hi[(size_t)c * 256 + k] = h;
    Wc_lo[(size_t)c * 256 + k] = l;
}

// ---------------------------------------------------------------------------
// kA1M: offset/attn GEMM via bf16 hi/lo MFMA (3-product f32 emulation)
// C = query(128x256) @ Wc^T(96x256)  ->  epilogue softmax + loc
// 4 waves: wm=(w&1)*64, wn=(w>>1)*48; 16x16x32 bf16 MFMA; XOR-swizzled LDS.
// ---------------------------------------------------------------------------
__global__ __launch_bounds__(256) void kA1M(const float* __restrict__ query,
                                            const float* __restrict__ refp,
                                            const short* __restrict__ Wc_hi,
                                            const short* __restrict__ Wc_lo,
                                            const float* __restrict__ b_off,
                                            const float* __restrict__ b_attn,
                                            float4* __restrict__ locattn) {
    __shared__ __align__(16) char smem[57344];
    short* As_hi = (short*)smem;              // 128x64 bf16 = 16384 B
    short* As_lo = (short*)(smem + 16384);    // 16384 B
    short* Bs_hi = (short*)(smem + 32768);    // 96x64 bf16 = 12288 B
    short* Bs_lo = (short*)(smem + 45056);    // 12288 B
    float* Ct    = (float*)smem;              // 128x100 f32 = 51200 B (reuse)

    const int t    = threadIdx.x;
    const int lane = t & 63;
    const int w    = t >> 6;
    const int wm   = (w & 1) * 64;
    const int wn   = (w >> 1) * 48;
    const int quad = lane >> 4;
    const int l16  = lane & 15;
    const int row0 = blockIdx.x * 128;

    f32x4 acc[4][3];
#pragma unroll
    for (int mt = 0; mt < 4; ++mt)
#pragma unroll
        for (int nt = 0; nt < 3; ++nt)
            acc[mt][nt] = (f32x4){0.f, 0.f, 0.f, 0.f};

    for (int k0c = 0; k0c < 4; ++k0c) {
        // stage A: query 128x64 f32 -> hi/lo bf16, coalesced float4 loads
#pragma unroll
        for (int i = 0; i < 8; ++i) {
            int f   = t + i * 256;       // 0..2047 float4 index
            int row = f >> 4;
            int kq4 = f & 15;
            float4 q = *(const float4*)&query[(size_t)(row0 + row) * 256 +
                                              k0c * 64 + kq4 * 4];
            short4 hv, lv;
            hv.x = f2bf_s(q.x); lv.x = f2bf_s(q.x - bf_s2f(hv.x));
            hv.y = f2bf_s(q.y); lv.y = f2bf_s(q.y - bf_s2f(hv.y));
            hv.z = f2bf_s(q.z); lv.z = f2bf_s(q.z - bf_s2f(hv.z));
            hv.w = f2bf_s(q.w); lv.w = f2bf_s(q.w - bf_s2f(hv.w));
            int base = row * 64 + (((kq4 >> 1) ^ (row & 7)) * 8) + (kq4 & 1) * 4;
            *(short4*)&As_hi[base] = hv;
            *(short4*)&As_lo[base] = lv;
        }
        // stage B: 96x64 bf16 hi/lo
#pragma unroll
        for (int i = 0; i < 3; ++i) {
            int idx = t + i * 256;       // 0..767 16B-block index
            int n   = idx >> 3;
            int kb  = idx & 7;
            int dst = n * 64 + ((kb ^ (n & 7)) * 8);
            *(uint4*)&Bs_hi[dst] =
                *(const uint4*)&Wc_hi[(size_t)n * 256 + k0c * 64 + kb * 8];
            *(uint4*)&Bs_lo[dst] =
                *(const uint4*)&Wc_lo[(size_t)n * 256 + k0c * 64 + kb * 8];
        }
        __syncthreads();

#pragma unroll
        for (int ks = 0; ks < 2; ++ks) {
            const int kq = ks * 4 + quad;
            bf16x8 ah[4], al[4], bh[3], bl[3];
#pragma unroll
            for (int mt = 0; mt < 4; ++mt) {
                int m = wm + mt * 16 + l16;
                ah[mt] = *(const bf16x8*)&As_hi[m * 64 + (kq ^ (m & 7)) * 8];
                al[mt] = *(const bf16x8*)&As_lo[m * 64 + (kq ^ (m & 7)) * 8];
            }
#pragma unroll
            for (int nt = 0; nt < 3; ++nt) {
                int n = wn + nt * 16 + l16;
                bh[nt] = *(const bf16x8*)&Bs_hi[n * 64 + (kq ^ (n & 7)) * 8];
                bl[nt] = *(const bf16x8*)&Bs_lo[n * 64 + (kq ^ (n & 7)) * 8];
            }
            // three product passes; dependent MFMAs on same acc are 12 apart
#pragma unroll
            for (int mt = 0; mt < 4; ++mt)
#pragma unroll
                for (int nt = 0; nt < 3; ++nt)
                    acc[mt][nt] = __builtin_amdgcn_mfma_f32_16x16x32_bf16(
                        ah[mt], bh[nt], acc[mt][nt], 0, 0, 0);
#pragma unroll
            for (int mt = 0; mt < 4; ++mt)
#pragma unroll
                for (int nt = 0; nt < 3; ++nt)
                    acc[mt][nt] = __builtin_amdgcn_mfma_f32_16x16x32_bf16(
                        ah[mt], bl[nt], acc[mt][nt], 0, 0, 0);
#pragma unroll
            for (int mt = 0; mt < 4; ++mt)
#pragma unroll
                for (int nt = 0; nt < 3; ++nt)
                    acc[mt][nt] = __builtin_amdgcn_mfma_f32_16x16x32_bf16(
                        al[mt], bh[nt], acc[mt][nt], 0, 0, 0);
        }
        __syncthreads();
    }

    // dump acc -> Ct[row][col], stride 100
#pragma unroll
    for (int mt = 0; mt < 4; ++mt) {
#pragma unroll
        for (int nt = 0; nt < 3; ++nt) {
            int col = wn + nt * 16 + l16;
#pragma unroll
            for (int rI = 0; rI < 4; ++rI) {
                int row = wm + mt * 16 + quad * 4 + rI;
                Ct[row * 100 + col] = acc[mt][nt][rI];
            }
        }
    }
    __syncthreads();

    // epilogue: per (row, h) softmax + sampling locations
    const int rg = t >> 3;
    const int h  = t & 7;
    float boff[8];
#pragma unroll
    for (int j = 0; j < 8; ++j) boff[j] = b_off[h * 8 + j];
    float batn[4];
#pragma unroll
    for (int j = 0; j < 4; ++j) batn[j] = b_attn[h * 4 + j];

#pragma unroll
    for (int r = 0; r < 4; ++r) {
        int row  = rg * 4 + r;
        int rowg = row0 + row;
        int bb   = rowg >> 13;
        int nn   = rowg & 8191;
        float rx = refp[(size_t)rowg * 2 + 0];
        float ry = refp[(size_t)rowg * 2 + 1];
        float4 lg4 = *(const float4*)&Ct[row * 100 + 64 + h * 4];
        float lg[4] = {lg4.x + batn[0], lg4.y + batn[1],
                       lg4.z + batn[2], lg4.w + batn[3]};
        float m = fmaxf(fmaxf(lg[0], lg[1]), fmaxf(lg[2], lg[3]));
        float e[4];
        float s = 0.f;
#pragma unroll
        for (int p = 0; p < 4; ++p) { e[p] = __expf(lg[p] - m); s += e[p]; }
        float inv = 1.f / s;
        float4 o0 = *(const float4*)&Ct[row * 100 + h * 8];
        float4 o1 = *(const float4*)&Ct[row * 100 + h * 8 + 4];
        float ox[4] = {o0.x + boff[0], o0.z + boff[2],
                       o1.x + boff[4], o1.z + boff[6]};
        float oy[4] = {o0.y + boff[1], o0.w + boff[3],
                       o1.y + boff[5], o1.w + boff[7]};
#pragma unroll
        for (int p = 0; p < 4; ++p) {
            float x = (rx * 2.f + ox[p]) * (W_ * 0.5f) - 0.5f;
            float y = (ry * 2.f + oy[p]) * (H_ * 0.5f) - 0.5f;
            locattn[(((size_t)bb * HH + h) * N_ + nn) * PP + p] =
                make_float4(x, y, e[p] * inv, 0.f);
        }
    }
}

// ---------------------------------------------------------------------------
// kA2: bilinear sampling + attention weighting -> mid (B*N, 256) bf16
// ---------------------------------------------------------------------------
__global__ __launch_bounds__(256) void kA2(const float4* __restrict__ locattn,
                                           const __hip_bfloat16* __restrict__ val,
                                           __hip_bfloat16* __restrict__ mid) {
    __shared__ float2 ow[64][4][4];

    const int t  = threadIdx.x;
    const int bh = blockIdx.y;
    const int b  = bh >> 3;
    const int h  = bh & 7;
    const int n0 = blockIdx.x * 64;

    {
        const int r = t >> 2;
        const int p = t & 3;
        float4 L = locattn[((size_t)bh * N_ + n0 + r) * PP + p];
        float x = L.x, y = L.y, a = L.z;
        float xf = floorf(x), yf = floorf(y);
        int x0 = (int)xf, y0 = (int)yf;
        int x1 = x0 + 1, y1 = y0 + 1;
        float wx1 = x - xf, wy1 = y - yf;
        float wx0 = 1.f - wx1, wy0 = 1.f - wy1;
        int cx0 = min(max(x0, 0), W_ - 1);
        int cx1 = min(max(x1, 0), W_ - 1);
        int cy0 = min(max(y0, 0), H_ - 1);
        int cy1 = min(max(y1, 0), H_ - 1);
        bool bx0 = (x0 >= 0) & (x0 < W_);
        bool bx1 = (x1 >= 0) & (x1 < W_);
        bool by0 = (y0 >= 0) & (y0 < H_);
        bool by1 = (y1 >= 0) & (y1 < H_);
        float w00 = a * wx0 * wy0 * ((bx0 & by0) ? 1.f : 0.f);
        float w10 = a * wx1 * wy0 * ((bx1 & by0) ? 1.f : 0.f);
        float w01 = a * wx0 * wy1 * ((bx0 & by1) ? 1.f : 0.f);
        float w11 = a * wx1 * wy1 * ((bx1 & by1) ? 1.f : 0.f);
        ow[r][p][0] = make_float2(__int_as_float(cy0 * W_ + cx0), w00);
        ow[r][p][1] = make_float2(__int_as_float(cy0 * W_ + cx1), w10);
        ow[r][p][2] = make_float2(__int_as_float(cy1 * W_ + cx0), w01);
        ow[r][p][3] = make_float2(__int_as_float(cy1 * W_ + cx1), w11);
    }
    __syncthreads();

    const int d  = t & 31;
    const int rg = t >> 5;
    const __hip_bfloat16* vb = val + (size_t)bh * HW * DD + d;
    __hip_bfloat16* mo = mid + ((size_t)b * N_ + n0) * C_ + h * DD + d;

#pragma unroll
    for (int j = 0; j < 8; ++j) {
        int r = rg * 8 + j;
        const float4* owp = (const float4*)&ow[r][0][0];
        float acc = 0.f;
#pragma unroll
        for (int p = 0; p < 4; ++p) {
            float4 u0 = owp[p * 2 + 0];
            float4 u1 = owp[p * 2 + 1];
            int o00 = __float_as_int(u0.x) * DD;
            int o10 = __float_as_int(u0.z) * DD;
            int o01 = __float_as_int(u1.x) * DD;
            int o11 = __float_as_int(u1.z) * DD;
            acc += u0.y * __bfloat162float(vb[o00]);
            acc += u0.w * __bfloat162float(vb[o10]);
            acc += u1.y * __bfloat162float(vb[o01]);
            acc += u1.w * __bfloat162float(vb[o11]);
        }
        mo[r * C_] = __float2bfloat16(acc);
    }
}

// ---------------------------------------------------------------------------
// kW: W_out (256x256 f32, k-major) -> Wt (256x256 bf16, n-major)
// ---------------------------------------------------------------------------
__global__ __launch_bounds__(256) void kW(const float* __restrict__ Wsrc,
                                          __hip_bfloat16* __restrict__ Wt) {
    __shared__ float tile[64][65];
    const int n0 = blockIdx.x * 64;
    const int k0 = blockIdx.y * 64;
    const int t  = threadIdx.x;
#pragma unroll
    for (int i = 0; i < 16; ++i) {
        int kk = i * 4 + (t >> 6);
        int nn = t & 63;
        tile[kk][nn] = Wsrc[(size_t)(k0 + kk) * 256 + n0 + nn];
    }
    __syncthreads();
#pragma unroll
    for (int i = 0; i < 16; ++i) {
        int nn = i * 4 + (t >> 6);
        int kk = t & 63;
        Wt[(size_t)(n0 + nn) * 256 + k0 + kk] = __float2bfloat16(tile[kk][nn]);
    }
}

// ---------------------------------------------------------------------------
// kC: out = mid (65536x256 bf16) @ Wt^T (n-major bf16) + bias, MFMA
// ---------------------------------------------------------------------------
__global__ __launch_bounds__(256) void kC(const short* __restrict__ mid,
                                          const short* __restrict__ Wt,
                                          const float* __restrict__ bias,
                                          float* __restrict__ out) {
    __shared__ __align__(16) short As[128 * 64];
    __shared__ __align__(16) short Bs[128 * 64];

    const int t    = threadIdx.x;
    const int lane = t & 63;
    const int w    = t >> 6;
    const int wm   = (w & 1) * 64;
    const int wn   = (w >> 1) * 64;
    const int row0 = blockIdx.x * 128;
    const int col0 = blockIdx.y * 128;

    f32x4 acc[4][4];
#pragma unroll
    for (int mt = 0; mt < 4; ++mt)
#pragma unroll
        for (int nt = 0; nt < 4; ++nt)
            acc[mt][nt] = (f32x4){0.f, 0.f, 0.f, 0.f};

    const int sr = t >> 3;
    const int kb = t & 7;

    for (int k0 = 0; k0 < 4; ++k0) {
#pragma unroll
        for (int i = 0; i < 4; ++i) {
            int row  = sr + i * 32;
            int kbs  = (kb ^ (row & 7)) * 8;
            *(uint4*)&As[row * 64 + kbs] =
                *(const uint4*)&mid[(size_t)(row0 + row) * 256 + k0 * 64 + kb * 8];
            *(uint4*)&Bs[row * 64 + kbs] =
                *(const uint4*)&Wt[(size_t)(col0 + row) * 256 + k0 * 64 + kb * 8];
        }
        __syncthreads();

#pragma unroll
        for (int ks = 0; ks < 2; ++ks) {
            const int kq = ks * 4 + (lane >> 4);
            bf16x8 af[4], bf[4];
#pragma unroll
            for (int mt = 0; mt < 4; ++mt) {
                int m = wm + mt * 16 + (lane & 15);
                af[mt] = *(const bf16x8*)&As[m * 64 + (kq ^ (m & 7)) * 8];
            }
#pragma unroll
            for (int nt = 0; nt < 4; ++nt) {
                int n = wn + nt * 16 + (lane & 15);
                bf[nt] = *(const bf16x8*)&Bs[n * 64 + (kq ^ (n & 7)) * 8];
            }
#pragma unroll
            for (int mt = 0; mt < 4; ++mt)
#pragma unroll
                for (int nt = 0; nt < 4; ++nt)
                    acc[mt][nt] = __builtin_amdgcn_mfma_f32_16x16x32_bf16(
                        af[mt], bf[nt], acc[mt][nt], 0, 0, 0);
        }
        __syncthreads();
    }

    const int cq = lane >> 4;
#pragma unroll
    for (int nt = 0; nt < 4; ++nt) {
        int col  = col0 + wn + nt * 16 + (lane & 15);
        float bv = bias[col];
#pragma unroll
        for (int mt = 0; mt < 4; ++mt) {
#pragma unroll
            for (int rI = 0; rI < 4; ++rI) {
                int rowg = row0 + wm + mt * 16 + cq * 4 + rI;
                out[(size_t)rowg * 256 + col] = acc[mt][nt][rI] + bv;
            }
        }
    }
}

// ---------------------------------------------------------------------------
// launcher
// ws: val     [0,          67108864)  B*8*HW*32 bf16
//     locattn [67108864,  100663296)  B*8*N*4 float4  (bh-major)
//     mid     [100663296, 134217728)  B*N*256 bf16
//     Wt      [134217728, 134348800)  256*256 bf16
//     Wc_hi   [134348800, 134397952)  96*256 bf16
//     Wc_lo   [134397952, 134447104)  96*256 bf16
// ---------------------------------------------------------------------------
extern "C" void kernel_launch(void* const* d_in, const int* in_sizes, int n_in,
                              void* d_out, int out_size, void* d_ws, size_t ws_size,
                              hipStream_t stream) {
    const float* query  = (const float*)d_in[0];
    const float* refp   = (const float*)d_in[1];
    const float* value  = (const float*)d_in[2];
    const float* W_off  = (const float*)d_in[3];
    const float* b_off  = (const float*)d_in[4];
    const float* W_attn = (const float*)d_in[5];
    const float* b_attn = (const float*)d_in[6];
    const float* W_out  = (const float*)d_in[7];
    const float* b_out  = (const float*)d_in[8];
    float* out = (float*)d_out;

    char*           ws      = (char*)d_ws;
    __hip_bfloat16* val     = (__hip_bfloat16*)(ws);
    float4*         locattn = (float4*)(ws + 67108864);
    __hip_bfloat16* mid     = (__hip_bfloat16*)(ws + 100663296);
    __hip_bfloat16* Wt      = (__hip_bfloat16*)(ws + 134217728);
    short*          Wc_hi   = (short*)(ws + 134348800);
    short*          Wc_lo   = (short*)(ws + 134397952);

    kT  <<<dim3(HW / 64, B_ * HH), 256, 0, stream>>>(value, val);
    kP  <<<dim3(96), 256, 0, stream>>>(W_off, W_attn, Wc_hi, Wc_lo);
    kW  <<<dim3(4, 4), 256, 0, stream>>>(W_out, Wt);
    kA1M<<<dim3((B_ * N_) / 128), 256, 0, stream>>>(query, refp, Wc_hi, Wc_lo,
                                                    b_off, b_attn, locattn);
    kA2 <<<dim3(N_ / 64, B_ * HH), 256, 0, stream>>>(locattn, val, mid);
    kC  <<<dim3((B_ * N_) / 128, C_ / 128), 256, 0, stream>>>(
        (const short*)mid, (const short*)Wt, b_out, out);
}